// Round 9
// baseline (1963.050 us; speedup 1.0000x reference)
//
#include <hip/hip_runtime.h>
#include <hip/hip_bf16.h>
#include <stdint.h>
#include <string.h>
#include <type_traits>

#define SUBU 20
#define E_NO 2000
#define I_NO 500
#define T_DATA 20000
#define T_SYNK 200
#define HBAS 3
#define SBAS 3
#define TPAD 20096          // 1256 * 16

// workspace float offsets
#define OFF_SYN  0          // [20][TPAD]  c[s][t] = TK*(syn + theta + rowsum)
#define OFF_INE  401920     // [20][TPAD]
#define OFF_INI  803840     // [20][TPAD]
#define OFF_KE   1205760    // [20][200]
#define OFF_KI   1209760    // [20][200]
#define OFF_IIR  1213760    // [20][16] folded IIR consts (A-side TK-scaled)
#define OFF_MW   1214760    // [20][KSTORE]  mwp = -2*TK*m
#define OFF_MIDX 1215000    // [20][KSTORE] ints
#define OFF_PAR  1215240    // TK*(theta+rowsum)[20], wsub0, vo, ksel(int at +23)
#define OFF_FLAG 1215264    // int bf16 flag
#define KSTORE   12

#define TKC 2.8853900817779268f   // 2*log2(e)

__device__ __forceinline__ float bf2f(unsigned short u){
  unsigned v = ((unsigned)u) << 16; float f; __builtin_memcpy(&f, &v, 4); return f;
}
__device__ __forceinline__ float ldany(const void* p, int i, int bf){
  return bf ? bf2f(((const unsigned short*)p)[i]) : ((const float*)p)[i];
}
__device__ __forceinline__ float ex2(float x){ return __builtin_amdgcn_exp2f(x); }
__device__ __forceinline__ float rcpa(float x){ return __builtin_amdgcn_rcpf(x); }

// ------- prep (with fused dtype detection): kernels, IIR, tables, params --
__global__ __launch_bounds__(512) void k_prep(
    const void* Se, const void* Cden, const void* Wsyn, const void* Tausyn,
    const void* Dsyn, const void* Whist, const void* Tauhist, const void* Dhist,
    const void* Wsub, const void* Vo, const void* Theta, float* ws){
  int* wsi = (int*)ws;
  const int tx = threadIdx.x;
  __shared__ int found, mx;
  if (tx == 0){ found = 0; mx = 0; }
  __syncthreads();
  {
    const unsigned* w = (const unsigned*)Se;
    int hit = 0;
    for (int i = tx; i < 8192; i += 512){
      unsigned x = w[i];
      if (x == 0x00003F80u || x == 0x3F803F80u) hit = 1;
    }
    if (hit) atomicOr(&found, 1);
  }
  __syncthreads();
  const int bf = found;
  if (tx == 0) wsi[OFF_FLAG] = bf;
  // synaptic kernels ke/ki [20][200]
  for (int idx = tx; idx < SUBU * T_SYNK; idx += 512){
    int s = idx / T_SYNK, t = idx % T_SYNK;
    for (int c = 0; c < 2; ++c){
      float delta = __expf(ldany(Dsyn, s*2 + c, bf));
      float acc = 0.f;
      for (int b = 0; b < SBAS; ++b){
        float tau = __expf(ldany(Tausyn, b*2 + c, bf));
        float w   = ldany(Wsyn, (s*SBAS + b)*2 + c, bf);
        float tt  = fmaxf((float)t - delta, 0.f) / tau;
        acc += w * tt * __expf(-tt);
      }
      ws[(c == 0 ? OFF_KE : OFF_KI) + s*T_SYNK + t] = acc;
    }
  }
  // folded per-lane IIR constants; A-side carries TK*w
  if (tx < SUBU * HBAS){
    int s = tx / HBAS, b = tx % HBAS;
    float tau = __expf(ldany(Tauhist, b, bf));
    float w   = TKC * ldany(Whist, s*HBAS + b, bf);
    float dl  = ldany(Dhist, s, bf);
    float rho = __expf(-1.f / tau);
    float e1  = __expf(-(1.f - dl) / tau);
    float g1  = ((1.f - dl) / tau) * e1;
    float kap = rho / tau;
    float* c = ws + OFF_IIR + s*16 + b*4;
    c[0] = rho;
    c[1] = w * kap;
    c[2] = w * g1;
    c[3] = e1;
    if (b == 2){
      float e49 = __expf(-(49.f - dl) / tau);
      float g49 = ((49.f - dl) / tau) * e49;
      ws[OFF_IIR + s*16 + 12] = w * (rho*g49 + kap*e49);  // cA (TK-scaled)
      ws[OFF_IIR + s*16 + 13] = rho * e49;                // cE (unscaled)
    }
  }
  // sparse gather weights mwp = -2*TK*C_den*W_sub ; rowsum fold into PAR
  if (tx < SUBU){
    int s = tx, cnt = 0;
    float rowsum = 0.f;
    for (int sp = 0; sp < SUBU; ++sp){
      float c = ldany(Cden, s*SUBU + sp, bf);
      if (c != 0.f && cnt < KSTORE){
        float m = c * ldany(Wsub, sp, bf);
        rowsum += m;
        ws[OFF_MW + s*KSTORE + cnt]  = -2.f * TKC * m;
        wsi[OFF_MIDX + s*KSTORE + cnt] = sp;
        ++cnt;
      }
    }
    for (int k = cnt; k < KSTORE; ++k){
      ws[OFF_MW + s*KSTORE + k] = 0.f; wsi[OFF_MIDX + s*KSTORE + k] = 0;
    }
    atomicMax(&mx, cnt);
    ws[OFF_PAR + s] = TKC * (ldany(Theta, s, bf) + rowsum);
  }
  __syncthreads();
  if (tx == 0){
    ws[OFF_PAR + SUBU]     = ldany(Wsub, 0, bf);
    ws[OFF_PAR + SUBU + 1] = ldany(Vo, 0, bf);
    wsi[OFF_PAR + 23] = (mx <= 3) ? 3 : (mx <= 4 ? 4 : (mx <= 5 ? 5 :
                        (mx <= 6 ? 6 : 12)));
  }
}

// ------- skinny GEMM (4 waves/block): in_T[s][t] = sum_e S[t][e]*C[s][e] --
template<int BF>
__device__ __forceinline__ void gemm_impl(const void* S, const void* C, int W,
                                          float* dst, int t0, int lane){
  float acc[4][SUBU];
  #pragma unroll
  for (int r = 0; r < 4; ++r)
    #pragma unroll
    for (int s = 0; s < SUBU; ++s) acc[r][s] = 0.f;
  for (int e = lane; e < W; e += 64){
    float s0 = ldany(S, (t0+0)*W + e, BF);
    float s1 = ldany(S, (t0+1)*W + e, BF);
    float s2 = ldany(S, (t0+2)*W + e, BF);
    float s3 = ldany(S, (t0+3)*W + e, BF);
    #pragma unroll
    for (int s = 0; s < SUBU; ++s){
      float c = ldany(C, s*W + e, BF);
      acc[0][s] = fmaf(s0, c, acc[0][s]);
      acc[1][s] = fmaf(s1, c, acc[1][s]);
      acc[2][s] = fmaf(s2, c, acc[2][s]);
      acc[3][s] = fmaf(s3, c, acc[3][s]);
    }
  }
  #pragma unroll
  for (int r = 0; r < 4; ++r){
    #pragma unroll
    for (int s = 0; s < SUBU; ++s){
      float v = acc[r][s];
      #pragma unroll
      for (int m = 32; m >= 1; m >>= 1) v += __shfl_xor(v, m, 64);
      if (lane == 0) dst[s*TPAD + t0 + r] = v;
    }
  }
}

__global__ __launch_bounds__(256) void k_gemm(const void* S, const void* C, int W,
                                              float* dst, const int* flagp){
  const int wave = threadIdx.x >> 6, lane = threadIdx.x & 63;
  const int t0 = blockIdx.x * 16 + wave * 4;
  if (*flagp) gemm_impl<1>(S, C, W, dst, t0, lane);
  else        gemm_impl<0>(S, C, W, dst, t0, lane);
}

// ------- causal conv (+theta/rowsum fold, TK scale): c[s][t] --------------
__global__ __launch_bounds__(256) void k_conv(float* ws){
  const int s  = blockIdx.y;
  const int t0 = blockIdx.x * 256;
  const float* ine = ws + OFF_INE + s*TPAD;
  const float* ini = ws + OFF_INI + s*TPAD;
  __shared__ float eL[455], iL[455], keL[T_SYNK], kiL[T_SYNK];
  for (int j = threadIdx.x; j < 455; j += 256){
    int t = t0 - 199 + j;
    bool ok = (t >= 0 && t < TPAD);
    eL[j] = ok ? ine[t] : 0.f;
    iL[j] = ok ? ini[t] : 0.f;
  }
  for (int j = threadIdx.x; j < T_SYNK; j += 256){
    keL[j] = ws[OFF_KE + s*T_SYNK + j];
    kiL[j] = ws[OFF_KI + s*T_SYNK + j];
  }
  __syncthreads();
  int t = t0 + threadIdx.x;
  if (t < TPAD){
    float a0 = 0.f, a1 = 0.f;
    #pragma unroll 4
    for (int k = 0; k < T_SYNK; ++k){
      a0 = fmaf(keL[k], eL[threadIdx.x + 199 - k], a0);
      a1 = fmaf(kiL[k], iL[threadIdx.x + 199 - k], a1);
    }
    ws[OFF_SYN + s*TPAD + t] = fmaf(TKC, a0 + a1, ws[OFF_PAR + s]);
  }
}

// ------- static float4 component helpers ----------------------------------
__device__ __forceinline__ float get4(const float4& a, const float4& b,
                                      const float4& c, const float4& d, int u){
  const float4& q = (u < 4) ? a : ((u < 8) ? b : ((u < 12) ? c : d));
  int r = u & 3;
  return (r == 0) ? q.x : ((r == 1) ? q.y : ((r == 2) ? q.z : q.w));
}
__device__ __forceinline__ void set4(float4& a, float4& b, float4& c, float4& d,
                                     int u, float v){
  float4& q = (u < 4) ? a : ((u < 8) ? b : ((u < 12) ? c : d));
  int r = u & 3;
  if (r == 0) q.x = v; else if (r == 1) q.y = v; else if (r == 2) q.z = v; else q.w = v;
}

// ------- scan body: per-step DS = KM bpermutes ONLY -----------------------
// Ring shifted +2: y[t] lives at pos (t+2)&63. yold block-reads become 4x
// aligned ds_read_b128 (optimal 8-phase, conflict-free); writes 8x b64.
template<int KM>
__device__ void scan_body(float* ws, void* outp, int bf, int lane, float* ring){
  const int* wsi = (const int*)ws;
  const int s = lane < SUBU ? lane : SUBU - 1;
  float* rbase = &ring[lane*68];
  {
    float4 z = make_float4(0.f, 0.f, 0.f, 0.f);
    float4* rq = (float4*)rbase;
    #pragma unroll
    for (int j = 0; j < 16; ++j) rq[j] = z;     // zero 64 ring entries
  }
  float mwp[KM]; int mad[KM];
  #pragma unroll
  for (int k = 0; k < KM; ++k){
    mwp[k] = ws[OFF_MW + s*KSTORE + k];
    mad[k] = wsi[OFF_MIDX + s*KSTORE + k] * 4;
  }
  const float* cc = ws + OFF_IIR + s*16;
  const float rh0 = cc[0],  kp0 = cc[1],  ay0 = cc[2],  ey0 = cc[3];
  const float rh1 = cc[4],  kp1 = cc[5],  ay1 = cc[6],  ey1 = cc[7];
  const float rh2 = cc[8],  kp2 = cc[9],  ay2 = cc[10], ey2 = cc[11];
  const float cA  = cc[12], cE  = cc[13];
  const float wsub0 = ws[OFF_PAR + SUBU];
  const float vo    = ws[OFF_PAR + SUBU + 1];
  const float* syncol = ws + OFF_SYN + s*TPAD;

  float A0=0.f,E0=0.f,A1=0.f,E1=0.f,A2=0.f,E2=0.f;
  float pb[KM];
  #pragma unroll
  for (int k = 0; k < KM; ++k) pb[k] = 0.5f;    // r for y=0
  float yprev = 0.f;                            // y[t-1]
  float4 u0 = *(const float4*)(syncol + 0);
  float4 u1 = *(const float4*)(syncol + 4);
  float4 u2 = *(const float4*)(syncol + 8);
  float4 u3 = *(const float4*)(syncol + 12);
  float4 n0, n1, n2, n3;
  float xpre = u0.x;                            // X[0] partial (h = 0)

  auto block16 = [&](auto PH_, int tbase, float4& b0, float4& b1, float4& b2,
                     float4& b3, float4& p0, float4& p1, float4& p2, float4& p3){
    constexpr int PH = decltype(PH_)::value;    // tbase & 63
    const float4* src = (const float4*)(syncol + tbase + 16);
    p0 = src[0]; p1 = src[1]; p2 = src[2]; p3 = src[3];
    // yold[u] = y[tbase-50+u] at ring pos (PH+16+u)&63 — contig, aligned b128
    constexpr int RO = (PH + 16) & 63;
    const float4* rr = (const float4*)(rbase + RO);
    float4 yo0 = rr[0], yo1 = rr[1], yo2 = rr[2], yo3 = rr[3];
    float4 ob0, ob1, ob2, ob3;                  // outputs (w*y+vo)
    float4 yb0, yb1, yb2, yb3;                  // y's for ring write
    #pragma unroll
    for (int u = 0; u < 16; ++u){
      // X[t] = xpre + sum_k mwp[k]*r_gathered[k]
      float acc0 = fmaf(mwp[0], pb[0], xpre);
      float acc1 = (KM > 1) ? mwp[1] * pb[1] : 0.f;
      #pragma unroll
      for (int k = 2; k < KM; ++k){
        if (k & 1) acc1 = fmaf(mwp[k], pb[k], acc1);
        else       acc0 = fmaf(mwp[k], pb[k], acc0);
      }
      float X  = acc0 + acc1;
      float r  = rcpa(ex2(X) + 1.f);
      // critical: issue next-step gathers immediately (only DS ops in queue)
      int rb = __float_as_int(r);
      #pragma unroll
      for (int k = 0; k < KM; ++k)
        pb[k] = __int_as_float(__builtin_amdgcn_ds_bpermute(mad[k], rb));
      float y = fmaf(-2.f, r, 1.f);             // y[t]
      float ro = get4(yo0, yo1, yo2, yo3, u);   // y[t-50]
      // folded IIR -> h[t+1]; input tap is y[t-1]
      float A0n = fmaf(rh0, A0, fmaf(kp0, E0, ay0 * yprev));
      E0 = fmaf(rh0, E0, ey0 * yprev); A0 = A0n;
      float A1n = fmaf(rh1, A1, fmaf(kp1, E1, ay1 * yprev));
      E1 = fmaf(rh1, E1, ey1 * yprev); A1 = A1n;
      float A2n = fmaf(rh2, A2, fmaf(kp2, E2, fmaf(-cA, ro, ay2 * yprev)));
      E2 = fmaf(rh2, E2, fmaf(-cE, ro, ey2 * yprev)); A2 = A2n;
      float h = (A0 + A1) + A2;
      float cn = (u < 15) ? get4(b0, b1, b2, b3, u + 1) : p0.x;
      xpre = cn + h;
      yprev = y;
      set4(yb0, yb1, yb2, yb3, u, y);
      set4(ob0, ob1, ob2, ob3, u, fmaf(y, wsub0, vo));
    }
    // ring writes: y[tbase+u] at pos (PH+2+u)&63, 8x aligned b64
    #pragma unroll
    for (int i = 0; i < 8; ++i){
      constexpr_hint:
      ;
      int pos = (PH + 2 + 2*i) & 63;            // folds to immediate per PH,i
      *(float2*)(rbase + pos) =
        make_float2(get4(yb0, yb1, yb2, yb3, 2*i),
                    get4(yb0, yb1, yb2, yb3, 2*i + 1));
    }
    if (lane == 0 && tbase + 16 <= T_DATA){
      if (bf){
        unsigned w[8];
        #pragma unroll
        for (int i = 0; i < 8; ++i){
          __hip_bfloat16 lo = __float2bfloat16(get4(ob0, ob1, ob2, ob3, 2*i));
          __hip_bfloat16 hi = __float2bfloat16(get4(ob0, ob1, ob2, ob3, 2*i + 1));
          unsigned short ulo, uhi;
          __builtin_memcpy(&ulo, &lo, 2); __builtin_memcpy(&uhi, &hi, 2);
          w[i] = (unsigned)ulo | ((unsigned)uhi << 16);
        }
        uint4* q = (uint4*)((__hip_bfloat16*)outp + tbase);
        q[0] = make_uint4(w[0], w[1], w[2], w[3]);
        q[1] = make_uint4(w[4], w[5], w[6], w[7]);
      } else {
        float4* q = (float4*)((float*)outp + tbase);
        q[0] = ob0; q[1] = ob1; q[2] = ob2; q[3] = ob3;
      }
    }
  };

  using P0  = std::integral_constant<int,0>;
  using P16 = std::integral_constant<int,16>;
  using P32 = std::integral_constant<int,32>;
  using P48 = std::integral_constant<int,48>;
  #pragma unroll 1
  for (int ib2 = 0; ib2 < 314; ++ib2){          // 314*64 = 20096 steps
    const int tb = ib2 * 64;
    block16(P0{},  tb,      u0, u1, u2, u3, n0, n1, n2, n3);
    block16(P16{}, tb + 16, n0, n1, n2, n3, u0, u1, u2, u3);
    block16(P32{}, tb + 32, u0, u1, u2, u3, n0, n1, n2, n3);
    block16(P48{}, tb + 48, n0, n1, n2, n3, u0, u1, u2, u3);
  }
}

// ------- single scan kernel: uniform runtime variant dispatch -------------
__global__ __launch_bounds__(64, 1) void k_scan(float* ws, void* outp){
  __shared__ float ring[64*68];
  const int* wsi = (const int*)ws;
  const int bf   = wsi[OFF_FLAG];
  const int ksel = wsi[OFF_PAR + 23];
  const int lane = threadIdx.x;
  switch (ksel){
    case 3:  scan_body<3>(ws, outp, bf, lane, ring); break;
    case 4:  scan_body<4>(ws, outp, bf, lane, ring); break;
    case 5:  scan_body<5>(ws, outp, bf, lane, ring); break;
    case 6:  scan_body<6>(ws, outp, bf, lane, ring); break;
    default: scan_body<12>(ws, outp, bf, lane, ring); break;
  }
}

// --------------------------------------------------------------------------
extern "C" void kernel_launch(void* const* d_in, const int* in_sizes, int n_in,
                              void* d_out, int out_size, void* d_ws, size_t ws_size,
                              hipStream_t stream){
  const void* S_e   = d_in[0];
  const void* S_i   = d_in[1];
  const void* C_den = d_in[2];
  const void* C_e   = d_in[3];
  const void* C_i   = d_in[4];
  const void* W_syn = d_in[5];
  const void* Tau_s = d_in[6];
  const void* D_syn = d_in[7];
  const void* W_hst = d_in[8];
  const void* Tau_h = d_in[9];
  const void* D_hst = d_in[10];
  const void* W_sub = d_in[11];
  const void* V_o   = d_in[12];
  const void* Theta = d_in[13];
  float* ws = (float*)d_ws;
  int* flagp = (int*)(ws + OFF_FLAG);

  k_prep<<<1, 512, 0, stream>>>(S_e, C_den, W_syn, Tau_s, D_syn, W_hst, Tau_h,
                                D_hst, W_sub, V_o, Theta, ws);
  k_gemm<<<1250, 256, 0, stream>>>(S_e, C_e, E_NO, ws + OFF_INE, flagp);
  k_gemm<<<1250, 256, 0, stream>>>(S_i, C_i, I_NO, ws + OFF_INI, flagp);
  dim3 cgrid(79, 20);
  k_conv<<<cgrid, 256, 0, stream>>>(ws);
  k_scan<<<1, 64, 0, stream>>>(ws, d_out);
}